// Round 3
// baseline (2749.152 us; speedup 1.0000x reference)
//
#include <hip/hip_runtime.h>

#define N_NODES 100000
#define N_EDGES 1600000
#define D 128           // D_IN == D_OUT == 128
#define D4 32           // D in float4 units

// ---------------------------------------------------------------------------
// Phase 1: support[N, 128] = x[N, 128] @ W[128, 128]   (fp32, vector ALU)
// Block: 256 threads, 32 rows per block. x rows staged in LDS.
// Thread t: col-group cg = t&31 (4 cols), row-group rg = t>>5 (4 rows).
// Each thread computes a 4-row x 4-col fp32 tile.
// W (64 KB) read from global: same 512 B row broadcast across the wave each
// k-step -> L1/L2 resident after first touch.
// ---------------------------------------------------------------------------
__device__ __forceinline__ void fma4(float4& a, float s, const float4& b) {
    a.x = fmaf(s, b.x, a.x);
    a.y = fmaf(s, b.y, a.y);
    a.z = fmaf(s, b.z, a.z);
    a.w = fmaf(s, b.w, a.w);
}

__global__ __launch_bounds__(256) void gemm_xw(
    const float* __restrict__ x, const float* __restrict__ W,
    float* __restrict__ support, int n)
{
    __shared__ float4 xs[32 * D4];   // 32 rows x 128 cols = 16 KB
    const int tid = threadIdx.x;
    const int block_row = blockIdx.x * 32;

    // Stage 32 rows of x (1024 float4) cooperatively, coalesced.
    const float4* xv = reinterpret_cast<const float4*>(x) + (size_t)block_row * D4;
    #pragma unroll
    for (int i = 0; i < 4; ++i) {
        int idx = tid + i * 256;
        xs[idx] = xv[idx];           // n % 32 == 0, always in range
    }
    __syncthreads();

    const int cg = tid & 31;         // column group (4 cols)
    const int rg = tid >> 5;         // row group (4 rows)
    const float4* Wv = reinterpret_cast<const float4*>(W);

    float4 acc0 = {0.f, 0.f, 0.f, 0.f};
    float4 acc1 = acc0, acc2 = acc0, acc3 = acc0;

    const int r0 = rg * 4;
    #pragma unroll 8
    for (int k4 = 0; k4 < D4; ++k4) {
        float4 xa = xs[(r0 + 0) * D4 + k4];
        float4 xb = xs[(r0 + 1) * D4 + k4];
        float4 xc = xs[(r0 + 2) * D4 + k4];
        float4 xd = xs[(r0 + 3) * D4 + k4];

        float4 w0 = Wv[(k4 * 4 + 0) * D4 + cg];
        fma4(acc0, xa.x, w0); fma4(acc1, xb.x, w0);
        fma4(acc2, xc.x, w0); fma4(acc3, xd.x, w0);

        float4 w1 = Wv[(k4 * 4 + 1) * D4 + cg];
        fma4(acc0, xa.y, w1); fma4(acc1, xb.y, w1);
        fma4(acc2, xc.y, w1); fma4(acc3, xd.y, w1);

        float4 w2 = Wv[(k4 * 4 + 2) * D4 + cg];
        fma4(acc0, xa.z, w2); fma4(acc1, xb.z, w2);
        fma4(acc2, xc.z, w2); fma4(acc3, xd.z, w2);

        float4 w3 = Wv[(k4 * 4 + 3) * D4 + cg];
        fma4(acc0, xa.w, w3); fma4(acc1, xb.w, w3);
        fma4(acc2, xc.w, w3); fma4(acc3, xd.w, w3);
    }

    float4* sv = reinterpret_cast<float4*>(support);
    sv[(size_t)(block_row + r0 + 0) * D4 + cg] = acc0;
    sv[(size_t)(block_row + r0 + 1) * D4 + cg] = acc1;
    sv[(size_t)(block_row + r0 + 2) * D4 + cg] = acc2;
    sv[(size_t)(block_row + r0 + 3) * D4 + cg] = acc3;
}

// ---------------------------------------------------------------------------
// Phase 2: out[row[e]] += ew[e] * support[col[e]]   (atomic scatter)
// 32 lanes per edge, 8 edges per 256-thread block. float4 support read
// (coalesced 512 B per edge), 4 scalar fp32 atomics per lane.
// ---------------------------------------------------------------------------
__global__ __launch_bounds__(256) void scatter_edges(
    const int* __restrict__ row, const int* __restrict__ col,
    const float* __restrict__ ew, const float* __restrict__ support,
    float* __restrict__ out)
{
    const int e = blockIdx.x * 8 + (threadIdx.x >> 5);
    if (e >= N_EDGES) return;
    const int lane = threadIdx.x & 31;

    const int r = row[e];
    const int c = col[e];
    const float w = ew[e];

    float4 s = reinterpret_cast<const float4*>(support)[(size_t)c * D4 + lane];
    float* o = out + (size_t)r * D + lane * 4;
    atomicAdd(o + 0, w * s.x);
    atomicAdd(o + 1, w * s.y);
    atomicAdd(o + 2, w * s.z);
    atomicAdd(o + 3, w * s.w);
}

extern "C" void kernel_launch(void* const* d_in, const int* in_sizes, int n_in,
                              void* d_out, int out_size, void* d_ws, size_t ws_size,
                              hipStream_t stream)
{
    const float* x      = (const float*)d_in[0];   // [N_NODES, 128]
    const int*   row    = (const int*)d_in[1];     // [N_EDGES]
    const int*   col    = (const int*)d_in[2];     // [N_EDGES]
    const float* ew     = (const float*)d_in[3];   // [N_EDGES]
    const float* weight = (const float*)d_in[4];   // [128, 128]
    float* out = (float*)d_out;                    // [N_NODES, 128]

    float* support = (float*)d_ws;                 // needs 51.2 MB of ws

    // support = x @ W
    gemm_xw<<<N_NODES / 32, 256, 0, stream>>>(x, weight, support, N_NODES);

    // out = 0 (harness poisons d_out; we accumulate atomically)
    hipMemsetAsync(d_out, 0, (size_t)N_NODES * D * sizeof(float), stream);

    // out[row] += ew * support[col]
    scatter_edges<<<N_EDGES / 8, 256, 0, stream>>>(row, col, ew, support, out);
}

// Round 4
// 598.450 us; speedup vs baseline: 4.5938x; 4.5938x over previous
//
#include <hip/hip_runtime.h>

#define N_NODES 100000
#define N_EDGES 1600000
#define D 128           // D_IN == D_OUT == 128
#define D4 32           // D in float4 units

// ---------------------------------------------------------------------------
// Phase 1: support[N, 128] = x[N, 128] @ W[128, 128]   (fp32, vector ALU)
// ---------------------------------------------------------------------------
__device__ __forceinline__ void fma4(float4& a, float s, const float4& b) {
    a.x = fmaf(s, b.x, a.x);
    a.y = fmaf(s, b.y, a.y);
    a.z = fmaf(s, b.z, a.z);
    a.w = fmaf(s, b.w, a.w);
}

__global__ __launch_bounds__(256) void gemm_xw(
    const float* __restrict__ x, const float* __restrict__ W,
    float* __restrict__ support, int n)
{
    __shared__ float4 xs[32 * D4];   // 32 rows x 128 cols = 16 KB
    const int tid = threadIdx.x;
    const int block_row = blockIdx.x * 32;

    const float4* xv = reinterpret_cast<const float4*>(x) + (size_t)block_row * D4;
    #pragma unroll
    for (int i = 0; i < 4; ++i) {
        int idx = tid + i * 256;
        xs[idx] = xv[idx];
    }
    __syncthreads();

    const int cg = tid & 31;         // column group (4 cols)
    const int rg = tid >> 5;         // row group (4 rows)
    const float4* Wv = reinterpret_cast<const float4*>(W);

    float4 acc0 = {0.f, 0.f, 0.f, 0.f};
    float4 acc1 = acc0, acc2 = acc0, acc3 = acc0;

    const int r0 = rg * 4;
    #pragma unroll 8
    for (int k4 = 0; k4 < D4; ++k4) {
        float4 xa = xs[(r0 + 0) * D4 + k4];
        float4 xb = xs[(r0 + 1) * D4 + k4];
        float4 xc = xs[(r0 + 2) * D4 + k4];
        float4 xd = xs[(r0 + 3) * D4 + k4];

        float4 w0 = Wv[(k4 * 4 + 0) * D4 + cg];
        fma4(acc0, xa.x, w0); fma4(acc1, xb.x, w0);
        fma4(acc2, xc.x, w0); fma4(acc3, xd.x, w0);

        float4 w1 = Wv[(k4 * 4 + 1) * D4 + cg];
        fma4(acc0, xa.y, w1); fma4(acc1, xb.y, w1);
        fma4(acc2, xc.y, w1); fma4(acc3, xd.y, w1);

        float4 w2 = Wv[(k4 * 4 + 2) * D4 + cg];
        fma4(acc0, xa.z, w2); fma4(acc1, xb.z, w2);
        fma4(acc2, xc.z, w2); fma4(acc3, xd.z, w2);

        float4 w3 = Wv[(k4 * 4 + 3) * D4 + cg];
        fma4(acc0, xa.w, w3); fma4(acc1, xb.w, w3);
        fma4(acc2, xc.w, w3); fma4(acc3, xd.w, w3);
    }

    float4* sv = reinterpret_cast<float4*>(support);
    sv[(size_t)(block_row + r0 + 0) * D4 + cg] = acc0;
    sv[(size_t)(block_row + r0 + 1) * D4 + cg] = acc1;
    sv[(size_t)(block_row + r0 + 2) * D4 + cg] = acc2;
    sv[(size_t)(block_row + r0 + 3) * D4 + cg] = acc3;
}

// ---------------------------------------------------------------------------
// CSR build (by destination row):
//   histogram -> single-WG scan (offsets + cursor) -> fill (col,w) pairs
// ---------------------------------------------------------------------------
__global__ __launch_bounds__(256) void histogram_rows(
    const int* __restrict__ row, int* __restrict__ count)
{
    int e = blockIdx.x * 256 + threadIdx.x;
    if (e < N_EDGES) atomicAdd(&count[row[e]], 1);
}

#define SCAN_T 1024
__global__ __launch_bounds__(SCAN_T) void scan_offsets(
    const int* __restrict__ count, int* __restrict__ offsets,
    int* __restrict__ cursor)
{
    __shared__ int buf[SCAN_T];
    __shared__ int carry_s;
    const int tid = threadIdx.x;
    if (tid == 0) { carry_s = 0; offsets[0] = 0; }
    __syncthreads();
    for (int base = 0; base < N_NODES; base += SCAN_T) {
        int i = base + tid;
        int v = (i < N_NODES) ? count[i] : 0;
        buf[tid] = v;
        __syncthreads();
        #pragma unroll
        for (int off = 1; off < SCAN_T; off <<= 1) {
            int add = (tid >= off) ? buf[tid - off] : 0;
            __syncthreads();
            buf[tid] += add;
            __syncthreads();
        }
        int incl = buf[tid];
        int carry = carry_s;                    // read (barrier-protected below)
        if (i < N_NODES) {
            offsets[i + 1] = carry + incl;
            cursor[i] = carry + incl - v;       // exclusive
        }
        __syncthreads();
        if (tid == SCAN_T - 1) carry_s = carry + incl;
        __syncthreads();
    }
}

__global__ __launch_bounds__(256) void fill_csr(
    const int* __restrict__ row, const int* __restrict__ col,
    const float* __restrict__ ew, int* __restrict__ cursor,
    int2* __restrict__ pairs)
{
    int e = blockIdx.x * 256 + threadIdx.x;
    if (e >= N_EDGES) return;
    int pos = atomicAdd(&cursor[row[e]], 1);
    pairs[pos] = make_int2(col[e], __float_as_int(ew[e]));
}

// ---------------------------------------------------------------------------
// Gather: one 64-lane wave per node. Lane holds float2 of the 128-wide acc.
// Per edge: broadcast (col,w) pair, coalesced 512 B support row read, FMA.
// One coalesced 512 B write per node. No fp32 atomics anywhere.
// ---------------------------------------------------------------------------
__global__ __launch_bounds__(256) void gather_nodes(
    const int* __restrict__ offsets, const int2* __restrict__ pairs,
    const float* __restrict__ support, float* __restrict__ out)
{
    const int wave = threadIdx.x >> 6;          // 0..3
    const int lane = threadIdx.x & 63;
    const int node = blockIdx.x * 4 + wave;
    if (node >= N_NODES) return;

    const int beg = offsets[node];
    const int end = offsets[node + 1];
    const float2* sv = reinterpret_cast<const float2*>(support);

    float2 acc = {0.f, 0.f};
    for (int e = beg; e < end; ++e) {
        int2 p = pairs[e];                      // same addr all lanes: broadcast
        float w = __int_as_float(p.y);
        float2 s = sv[(size_t)p.x * 64 + lane];
        acc.x = fmaf(w, s.x, acc.x);
        acc.y = fmaf(w, s.y, acc.y);
    }
    reinterpret_cast<float2*>(out)[(size_t)node * 64 + lane] = acc;
}

// ---------------------------------------------------------------------------
// Fallback (ws too small): atomic scatter, proven correct in R3.
// ---------------------------------------------------------------------------
__global__ __launch_bounds__(256) void scatter_edges(
    const int* __restrict__ row, const int* __restrict__ col,
    const float* __restrict__ ew, const float* __restrict__ support,
    float* __restrict__ out)
{
    const int e = blockIdx.x * 8 + (threadIdx.x >> 5);
    if (e >= N_EDGES) return;
    const int lane = threadIdx.x & 31;

    const int r = row[e];
    const int c = col[e];
    const float w = ew[e];

    float4 s = reinterpret_cast<const float4*>(support)[(size_t)c * D4 + lane];
    float* o = out + (size_t)r * D + lane * 4;
    atomicAdd(o + 0, w * s.x);
    atomicAdd(o + 1, w * s.y);
    atomicAdd(o + 2, w * s.z);
    atomicAdd(o + 3, w * s.w);
}

extern "C" void kernel_launch(void* const* d_in, const int* in_sizes, int n_in,
                              void* d_out, int out_size, void* d_ws, size_t ws_size,
                              hipStream_t stream)
{
    const float* x      = (const float*)d_in[0];   // [N_NODES, 128]
    const int*   row    = (const int*)d_in[1];     // [N_EDGES]
    const int*   col    = (const int*)d_in[2];     // [N_EDGES]
    const float* ew     = (const float*)d_in[3];   // [N_EDGES]
    const float* weight = (const float*)d_in[4];   // [128, 128]
    float* out = (float*)d_out;                    // [N_NODES, 128]

    char* ws = (char*)d_ws;
    const size_t off_support = 0;                               // 51,200,000 B
    const size_t off_pairs   = off_support + (size_t)N_NODES * D * 4;   // 12.8 MB
    const size_t off_count   = off_pairs + (size_t)N_EDGES * 8;         // 400 KB
    const size_t off_offsets = off_count + (size_t)N_NODES * 4;         // 400 KB+
    const size_t off_cursor  = off_offsets + ((size_t)(N_NODES + 1) * 4 + 15 & ~(size_t)15);
    const size_t required    = off_cursor + (size_t)N_NODES * 4;

    float* support = (float*)(ws + off_support);

    if (ws_size >= required) {
        int2* pairs   = (int2*)(ws + off_pairs);
        int*  count   = (int*)(ws + off_count);
        int*  offsets = (int*)(ws + off_offsets);
        int*  cursor  = (int*)(ws + off_cursor);

        // --- CSR build (independent of GEMM) ---
        hipMemsetAsync(count, 0, (size_t)N_NODES * 4, stream);
        histogram_rows<<<(N_EDGES + 255) / 256, 256, 0, stream>>>(row, count);
        scan_offsets<<<1, SCAN_T, 0, stream>>>(count, offsets, cursor);
        fill_csr<<<(N_EDGES + 255) / 256, 256, 0, stream>>>(row, col, ew, cursor, pairs);

        // --- GEMM last before gather: keeps support hot in L2/L3 ---
        gemm_xw<<<N_NODES / 32, 256, 0, stream>>>(x, weight, support, N_NODES);

        // --- Gather: writes every output row (no memset needed) ---
        gather_nodes<<<(N_NODES + 3) / 4, 256, 0, stream>>>(offsets, pairs, support, out);
    } else {
        // Fallback: atomic scatter path (R3)
        gemm_xw<<<N_NODES / 32, 256, 0, stream>>>(x, weight, support, N_NODES);
        hipMemsetAsync(d_out, 0, (size_t)N_NODES * D * sizeof(float), stream);
        scatter_edges<<<N_EDGES / 8, 256, 0, stream>>>(row, col, ew, support, out);
    }
}

// Round 5
// 381.956 us; speedup vs baseline: 7.1976x; 1.5668x over previous
//
#include <hip/hip_runtime.h>

#define N_NODES 100000
#define N_EDGES 1600000
#define D 128           // D_IN == D_OUT == 128
#define D4 32           // D in float4 units

#define SCAN_BLK 1024
#define SCAN_NB ((N_NODES + SCAN_BLK - 1) / SCAN_BLK)   // 98

// ---------------------------------------------------------------------------
// Phase 1: support[N, 128] = x[N, 128] @ W[128, 128]   (fp32, vector ALU)
// ---------------------------------------------------------------------------
__device__ __forceinline__ void fma4(float4& a, float s, const float4& b) {
    a.x = fmaf(s, b.x, a.x);
    a.y = fmaf(s, b.y, a.y);
    a.z = fmaf(s, b.z, a.z);
    a.w = fmaf(s, b.w, a.w);
}

__global__ __launch_bounds__(256) void gemm_xw(
    const float* __restrict__ x, const float* __restrict__ W,
    float* __restrict__ support, int n)
{
    __shared__ float4 xs[32 * D4];   // 32 rows x 128 cols = 16 KB
    const int tid = threadIdx.x;
    const int block_row = blockIdx.x * 32;

    const float4* xv = reinterpret_cast<const float4*>(x) + (size_t)block_row * D4;
    #pragma unroll
    for (int i = 0; i < 4; ++i) {
        int idx = tid + i * 256;
        xs[idx] = xv[idx];
    }
    __syncthreads();

    const int cg = tid & 31;         // column group (4 cols)
    const int rg = tid >> 5;         // row group (4 rows)
    const float4* Wv = reinterpret_cast<const float4*>(W);

    float4 acc0 = {0.f, 0.f, 0.f, 0.f};
    float4 acc1 = acc0, acc2 = acc0, acc3 = acc0;

    const int r0 = rg * 4;
    #pragma unroll 8
    for (int k4 = 0; k4 < D4; ++k4) {
        float4 xa = xs[(r0 + 0) * D4 + k4];
        float4 xb = xs[(r0 + 1) * D4 + k4];
        float4 xc = xs[(r0 + 2) * D4 + k4];
        float4 xd = xs[(r0 + 3) * D4 + k4];

        float4 w0 = Wv[(k4 * 4 + 0) * D4 + cg];
        fma4(acc0, xa.x, w0); fma4(acc1, xb.x, w0);
        fma4(acc2, xc.x, w0); fma4(acc3, xd.x, w0);

        float4 w1 = Wv[(k4 * 4 + 1) * D4 + cg];
        fma4(acc0, xa.y, w1); fma4(acc1, xb.y, w1);
        fma4(acc2, xc.y, w1); fma4(acc3, xd.y, w1);

        float4 w2 = Wv[(k4 * 4 + 2) * D4 + cg];
        fma4(acc0, xa.z, w2); fma4(acc1, xb.z, w2);
        fma4(acc2, xc.z, w2); fma4(acc3, xd.z, w2);

        float4 w3 = Wv[(k4 * 4 + 3) * D4 + cg];
        fma4(acc0, xa.w, w3); fma4(acc1, xb.w, w3);
        fma4(acc2, xc.w, w3); fma4(acc3, xd.w, w3);
    }

    float4* sv = reinterpret_cast<float4*>(support);
    sv[(size_t)(block_row + r0 + 0) * D4 + cg] = acc0;
    sv[(size_t)(block_row + r0 + 1) * D4 + cg] = acc1;
    sv[(size_t)(block_row + r0 + 2) * D4 + cg] = acc2;
    sv[(size_t)(block_row + r0 + 3) * D4 + cg] = acc3;
}

// ---------------------------------------------------------------------------
// CSR build: histogram -> hierarchical scan (3 kernels) -> fill (col,w) pairs
// ---------------------------------------------------------------------------
__global__ __launch_bounds__(256) void histogram_rows(
    const int* __restrict__ row, int* __restrict__ count)
{
    int e = blockIdx.x * 256 + threadIdx.x;
    if (e < N_EDGES) atomicAdd(&count[row[e]], 1);
}

// 1) per-block sum of 1024 counts -> block_sums[98]
__global__ __launch_bounds__(256) void reduce_counts(
    const int* __restrict__ count, int* __restrict__ block_sums)
{
    const int tid = threadIdx.x;
    const int base = blockIdx.x * SCAN_BLK;
    int v = 0;
    #pragma unroll
    for (int i = 0; i < 4; ++i) {
        int idx = base + tid + i * 256;
        if (idx < N_NODES) v += count[idx];
    }
    // wave reduce (64 lanes)
    #pragma unroll
    for (int off = 32; off > 0; off >>= 1) v += __shfl_down(v, off, 64);
    __shared__ int ws_[4];
    if ((tid & 63) == 0) ws_[tid >> 6] = v;
    __syncthreads();
    if (tid == 0) block_sums[blockIdx.x] = ws_[0] + ws_[1] + ws_[2] + ws_[3];
}

// 2) exclusive scan of 98 block sums in one small block
__global__ __launch_bounds__(128) void scan_block_sums(int* __restrict__ block_sums)
{
    __shared__ int buf[128];
    const int tid = threadIdx.x;
    int v = (tid < SCAN_NB) ? block_sums[tid] : 0;
    buf[tid] = v;
    __syncthreads();
    #pragma unroll
    for (int off = 1; off < 128; off <<= 1) {
        int add = (tid >= off) ? buf[tid - off] : 0;
        __syncthreads();
        buf[tid] += add;
        __syncthreads();
    }
    if (tid < SCAN_NB) block_sums[tid] = buf[tid] - v;   // exclusive
}

// 3) per-block scan of counts + carry -> offsets[i+1], cursor[i]
__global__ __launch_bounds__(SCAN_BLK) void scan_apply(
    const int* __restrict__ count, const int* __restrict__ block_sums,
    int* __restrict__ offsets, int* __restrict__ cursor)
{
    __shared__ int buf[SCAN_BLK];
    const int tid = threadIdx.x;
    const int i = blockIdx.x * SCAN_BLK + tid;
    const int carry = block_sums[blockIdx.x];
    int v = (i < N_NODES) ? count[i] : 0;
    buf[tid] = v;
    __syncthreads();
    #pragma unroll
    for (int off = 1; off < SCAN_BLK; off <<= 1) {
        int add = (tid >= off) ? buf[tid - off] : 0;
        __syncthreads();
        buf[tid] += add;
        __syncthreads();
    }
    if (i < N_NODES) {
        int incl = carry + buf[tid];
        offsets[i + 1] = incl;
        cursor[i] = incl - v;
    }
    if (i == 0) offsets[0] = 0;
}

__global__ __launch_bounds__(256) void fill_csr(
    const int* __restrict__ row, const int* __restrict__ col,
    const float* __restrict__ ew, int* __restrict__ cursor,
    int2* __restrict__ pairs)
{
    int e = blockIdx.x * 256 + threadIdx.x;
    if (e >= N_EDGES) return;
    int pos = atomicAdd(&cursor[row[e]], 1);
    pairs[pos] = make_int2(col[e], __float_as_int(ew[e]));
}

// ---------------------------------------------------------------------------
// Gather: one 64-lane wave per node, float2 per lane. Edge loop unrolled x4
// so 4 independent (pair -> support-row) load chains are in flight.
// ---------------------------------------------------------------------------
__global__ __launch_bounds__(256) void gather_nodes(
    const int* __restrict__ offsets, const int2* __restrict__ pairs,
    const float* __restrict__ support, float* __restrict__ out)
{
    const int wave = threadIdx.x >> 6;          // 0..3
    const int lane = threadIdx.x & 63;
    const int node = blockIdx.x * 4 + wave;
    if (node >= N_NODES) return;

    const int beg = offsets[node];
    const int end = offsets[node + 1];
    const float2* sv = reinterpret_cast<const float2*>(support);

    float2 acc = {0.f, 0.f};
    int e = beg;
    for (; e + 4 <= end; e += 4) {
        int2 p0 = pairs[e];
        int2 p1 = pairs[e + 1];
        int2 p2 = pairs[e + 2];
        int2 p3 = pairs[e + 3];
        float2 s0 = sv[(size_t)p0.x * 64 + lane];
        float2 s1 = sv[(size_t)p1.x * 64 + lane];
        float2 s2 = sv[(size_t)p2.x * 64 + lane];
        float2 s3 = sv[(size_t)p3.x * 64 + lane];
        float w0 = __int_as_float(p0.y), w1 = __int_as_float(p1.y);
        float w2 = __int_as_float(p2.y), w3 = __int_as_float(p3.y);
        acc.x = fmaf(w0, s0.x, acc.x); acc.y = fmaf(w0, s0.y, acc.y);
        acc.x = fmaf(w1, s1.x, acc.x); acc.y = fmaf(w1, s1.y, acc.y);
        acc.x = fmaf(w2, s2.x, acc.x); acc.y = fmaf(w2, s2.y, acc.y);
        acc.x = fmaf(w3, s3.x, acc.x); acc.y = fmaf(w3, s3.y, acc.y);
    }
    for (; e < end; ++e) {
        int2 p = pairs[e];
        float w = __int_as_float(p.y);
        float2 s = sv[(size_t)p.x * 64 + lane];
        acc.x = fmaf(w, s.x, acc.x);
        acc.y = fmaf(w, s.y, acc.y);
    }
    reinterpret_cast<float2*>(out)[(size_t)node * 64 + lane] = acc;
}

// ---------------------------------------------------------------------------
// Fallback (ws too small): atomic scatter, proven correct in R3.
// ---------------------------------------------------------------------------
__global__ __launch_bounds__(256) void scatter_edges(
    const int* __restrict__ row, const int* __restrict__ col,
    const float* __restrict__ ew, const float* __restrict__ support,
    float* __restrict__ out)
{
    const int e = blockIdx.x * 8 + (threadIdx.x >> 5);
    if (e >= N_EDGES) return;
    const int lane = threadIdx.x & 31;

    const int r = row[e];
    const int c = col[e];
    const float w = ew[e];

    float4 s = reinterpret_cast<const float4*>(support)[(size_t)c * D4 + lane];
    float* o = out + (size_t)r * D + lane * 4;
    atomicAdd(o + 0, w * s.x);
    atomicAdd(o + 1, w * s.y);
    atomicAdd(o + 2, w * s.z);
    atomicAdd(o + 3, w * s.w);
}

extern "C" void kernel_launch(void* const* d_in, const int* in_sizes, int n_in,
                              void* d_out, int out_size, void* d_ws, size_t ws_size,
                              hipStream_t stream)
{
    const float* x      = (const float*)d_in[0];   // [N_NODES, 128]
    const int*   row    = (const int*)d_in[1];     // [N_EDGES]
    const int*   col    = (const int*)d_in[2];     // [N_EDGES]
    const float* ew     = (const float*)d_in[3];   // [N_EDGES]
    const float* weight = (const float*)d_in[4];   // [128, 128]
    float* out = (float*)d_out;                    // [N_NODES, 128]

    char* ws = (char*)d_ws;
    const size_t off_support = 0;                               // 51,200,000 B
    const size_t off_pairs   = off_support + (size_t)N_NODES * D * 4;   // 12.8 MB
    const size_t off_count   = off_pairs + (size_t)N_EDGES * 8;         // 400 KB
    const size_t off_offsets = off_count + (size_t)N_NODES * 4;
    const size_t off_cursor  = off_offsets + (((size_t)(N_NODES + 1) * 4 + 15) & ~(size_t)15);
    const size_t off_bsums   = off_cursor + (size_t)N_NODES * 4;
    const size_t required    = off_bsums + (size_t)SCAN_NB * 4;

    float* support = (float*)(ws + off_support);

    if (ws_size >= required) {
        int2* pairs   = (int2*)(ws + off_pairs);
        int*  count   = (int*)(ws + off_count);
        int*  offsets = (int*)(ws + off_offsets);
        int*  cursor  = (int*)(ws + off_cursor);
        int*  bsums   = (int*)(ws + off_bsums);

        // --- CSR build ---
        hipMemsetAsync(count, 0, (size_t)N_NODES * 4, stream);
        histogram_rows<<<(N_EDGES + 255) / 256, 256, 0, stream>>>(row, count);
        reduce_counts<<<SCAN_NB, 256, 0, stream>>>(count, bsums);
        scan_block_sums<<<1, 128, 0, stream>>>(bsums);
        scan_apply<<<SCAN_NB, SCAN_BLK, 0, stream>>>(count, bsums, offsets, cursor);
        fill_csr<<<(N_EDGES + 255) / 256, 256, 0, stream>>>(row, col, ew, cursor, pairs);

        // --- GEMM last before gather: keeps support hot in L2/L3 ---
        gemm_xw<<<N_NODES / 32, 256, 0, stream>>>(x, weight, support, N_NODES);

        // --- Gather: writes every output row (no memset needed) ---
        gather_nodes<<<(N_NODES + 3) / 4, 256, 0, stream>>>(offsets, pairs, support, out);
    } else {
        // Fallback: atomic scatter path (R3)
        gemm_xw<<<N_NODES / 32, 256, 0, stream>>>(x, weight, support, N_NODES);
        hipMemsetAsync(d_out, 0, (size_t)N_NODES * D * sizeof(float), stream);
        scatter_edges<<<N_EDGES / 8, 256, 0, stream>>>(row, col, ew, support, out);
    }
}